// Round 12
// baseline (30890.857 us; speedup 1.0000x reference)
//
#include <hip/hip_runtime.h>

// ---------------------------------------------------------------------------
// RevRNN persistent kernel, round 15: quarter-column WGs, state mostly local.
// Evidence base: r3->r7 (-38%) came from shrinking the exchange surface;
// r12 killed congestion theory; r14 killed the latency-domain theory (FETCH
// 540->215MB proved L2-containment worked, time did NOT improve). So: shrink
// the surface again, keeping r7's proven merged-poll protocol byte-for-byte.
// - 16 WGs x 512 thr: WG(b,q) = 16 batch rows x 64 o-cols (8 waves x 8 cols
//   -> per-wave W budget = r7's 128 VGPR; avoids r12's VGPR-256 trap).
// - Own-quarter state: gate -> LDS directly (never leaves the WG). Only 3
//   partner quarters cross WGs (tagged u64 cells, r7 layout). Mean partials
//   as r7 (pa[col*4+b], producer = WG(b, q(col))).
// - Per-thread poll: 12 -> 5 words (3 state + 2 mean); producer fan 12 -> 5.
//   Poll payloads go straight to the LDS A-fragment buffer.
// - Everything else r7 verbatim: self-validating tags, fire-and-forget
//   publish, consumer-side centering, __syncthreads x2 per phase, xf
//   prefetch, dual MFMA chains, branch-free tanh, sticky alive guard.
// ---------------------------------------------------------------------------

#define T_TOT 2056
#define S_SEQ 2048

typedef _Float16 f16x8 __attribute__((ext_vector_type(8)));
typedef float f32x4 __attribute__((ext_vector_type(4)));

// exchange arrays: static device globals
__device__ unsigned long long g_st0[8192];  // [b][q][row 0..15][colpair 0..31]
__device__ unsigned long long g_st1[8192];
__device__ unsigned long long g_pa0[1024];  // [256 ocol][4 b-groups]
__device__ unsigned long long g_pa1[1024];

__global__ void init_ws() {
  const int i = (int)blockIdx.x * 256 + (int)threadIdx.x;  // 8192 threads
  g_st0[i] = 0ull;
  g_st1[i] = 0ull;
  if (i < 1024) { g_pa0[i] = 0ull; g_pa1[i] = 0ull; }
}

#define AL(P) __hip_atomic_load((P), __ATOMIC_RELAXED, __HIP_MEMORY_SCOPE_AGENT)
#define AS(P, V)                                                               \
  __hip_atomic_store((P), (V), __ATOMIC_RELAXED, __HIP_MEMORY_SCOPE_AGENT)
#define TOK(Q) ((unsigned)((Q) >> 32) >= tg_)

// One phase: sticky merged 5-word poll -> partner payload to LDS + pairsum
// -> barrier -> mean -> barrier -> centered MFMA -> gate -> own state to LDS
// + tagged publish (fire-and-forget). 2 barriers/phase total.
#define PHASE(WS, HIN, HOUT, SIN, PIN, TAGIN, SOUT, POUT, TAGOUT, RAW)         \
  {                                                                            \
    const unsigned tg_ = (unsigned)(TAGIN);                                    \
    const unsigned long long* mp_ =                                            \
        (PIN) + 4 * (tid & 255) + 2 * (tid >> 8);                              \
    const unsigned long long* sa_ = (SIN) + (size_t)(b * 4 + qa) * 512 + tid;  \
    const unsigned long long* sb_ = (SIN) + (size_t)(b * 4 + qb) * 512 + tid;  \
    const unsigned long long* sc_ = (SIN) + (size_t)(b * 4 + qc) * 512 + tid;  \
    unsigned long long m0_ = AL(mp_), m1_ = AL(mp_ + 1);                       \
    unsigned long long s0_ = AL(sa_), s1_ = AL(sb_), s2_ = AL(sc_);            \
    int it_ = 0;                                                               \
    for (;;) {                                                                 \
      if (TOK(m0_) && TOK(m1_) && TOK(s0_) && TOK(s1_) && TOK(s2_)) break;     \
      if (!alive || ++it_ > (1 << 16)) { alive = 0; break; }                   \
      if (!TOK(m0_)) m0_ = AL(mp_);                                            \
      if (!TOK(m1_)) m1_ = AL(mp_ + 1);                                        \
      if (!TOK(s0_)) s0_ = AL(sa_);                                            \
      if (!TOK(s1_)) s1_ = AL(sb_);                                            \
      if (!TOK(s2_)) s2_ = AL(sc_);                                            \
    }                                                                          \
    ps[tid >> 8][tid & 255] =                                                  \
        __uint_as_float((unsigned)m0_) + __uint_as_float((unsigned)m1_);       \
    {                                                                          \
      const int r_ = tid >> 5, p_ = tid & 31;                                  \
      HIN[r_][32 * qa + p_] = (unsigned)s0_;                                   \
      HIN[r_][32 * qb + p_] = (unsigned)s1_;                                   \
      HIN[r_][32 * qc + p_] = (unsigned)s2_;                                   \
    }                                                                          \
    __syncthreads();                                                           \
    if (tid < 256)                                                             \
      mean_h[tid] = (_Float16)((ps[0][tid] + ps[1][tid]) * 0.015625f);         \
    __syncthreads();                                                           \
    _Pragma("unroll")                                                          \
    for (int kk = 0; kk < 8; ++kk) {                                           \
      const f16x8 sv_ = *(const f16x8*)((const _Float16*)&HIN[0][0] +          \
                                        n * 272 + kk * 32 + kq * 8);           \
      const f16x8 mv_ = *(const f16x8*)&mean_h[kk * 32 + kq * 8];              \
      if (kk & 1)                                                              \
        acc1 = __builtin_amdgcn_mfma_f32_16x16x32_f16(sv_ - mv_, (WS)[kk],     \
                                                      acc1, 0, 0, 0);          \
      else                                                                     \
        acc0 = __builtin_amdgcn_mfma_f32_16x16x32_f16(sv_ - mv_, (WS)[kk],     \
                                                      acc0, 0, 0, 0);          \
    }                                                                          \
    float nv_[4], ssum_ = 0.f;                                                 \
    _Pragma("unroll")                                                          \
    for (int r = 0; r < 4; ++r) {                                              \
      const float z = acc0[r] + acc1[r];                                       \
      const float p = __shfl_xor(z, 8);                                        \
      const float z0 = (n < 8) ? z : p;                                        \
      const float z1 = (n < 8) ? p : z;                                        \
      /* branch-free tanh: clamp +-10, (e-1)/(e+1); err << f16 quantization */ \
      const float z1c = fminf(fmaxf(z1, -10.f), 10.f);                         \
      const float e2 = __expf(2.f * z1c);                                      \
      const float th = (e2 - 1.f) * __builtin_amdgcn_rcpf(e2 + 1.f);           \
      const float cv = fminf(fmaxf(z0, 0.f), 6.f) * th;                        \
      const float o = ((RAW)[r] + cv) * 0.5f;                                  \
      (RAW)[r] = o; nv_[r] = o; ssum_ += o;                                    \
    }                                                                          \
    ssum_ += __shfl_xor(ssum_, 16);                                            \
    ssum_ += __shfl_xor(ssum_, 32);                                            \
    _Pragma("unroll")                                                          \
    for (int r = 0; r < 4; ++r) {                                              \
      union { _Float16 h; unsigned short u; } hb_;                             \
      hb_.h = (_Float16)nv_[r];                                                \
      const unsigned pr_ = (unsigned)__shfl_xor((int)hb_.u, 1) & 0xFFFFu;      \
      if ((n & 1) == 0 && n < 8) {                                             \
        const unsigned dw_ = (unsigned)hb_.u | (pr_ << 16);                    \
        HOUT[kq * 4 + r][32 * q + 4 * w + (n >> 1)] = dw_;                     \
        AS((SOUT) + (size_t)(b * 4 + q) * 512 + (kq * 4 + r) * 32 + 4 * w +    \
               (n >> 1),                                                       \
           ((unsigned long long)(unsigned)(TAGOUT) << 32) |                    \
               (unsigned long long)dw_);                                       \
      }                                                                        \
    }                                                                          \
    if (kq == 0 && n < 8)                                                      \
      AS((POUT) + (size_t)ocg * 4 + b,                                         \
         ((unsigned long long)(unsigned)(TAGOUT) << 32) |                      \
             (unsigned long long)__float_as_uint(ssum_));                      \
  }

__launch_bounds__(512)
__global__ void rnn_kernel(const float* __restrict__ xg,
                           const float* __restrict__ hs,
                           const float* __restrict__ W0,
                           const float* __restrict__ W1,
                           float* __restrict__ out) {
  const int wgid = (int)blockIdx.x;        // 0..15
  const int b = wgid & 3;                  // batch group: rows 16b..16b+15
  const int q = wgid >> 2;                 // col quarter: o-cols 64q..64q+63
  const int qa = (q + 1) & 3, qb = (q + 2) & 3, qc = (q + 3) & 3;
  const int tid = (int)threadIdx.x;        // 0..511
  const int w = tid >> 6;                  // wave 0..7
  const int ln = tid & 63;
  const int n = ln & 15;                   // packed col in tile / A-row
  const int kq = ln >> 4;                  // quad 0..3
  const int ocg = 64 * q + 8 * w + (n & 7);        // owned output column
  const int wrow = (n < 8) ? ocg : (256 + ocg);    // packed W row (z0|z1)

  __shared__ __align__(16) unsigned h0u[16][136];  // state bufs, 272-f16 pad
  __shared__ __align__(16) unsigned h1u[16][136];
  __shared__ float ps[2][256];                     // mean pairsums
  __shared__ __align__(16) _Float16 mean_h[256];

  // ---- preload W fragments (state part + x part) into registers ----
  f16x8 w0s[8], w0x[8], w1s[8], w1x[8];
  float w0pa, w0pb, w1pa, w1pb;
  {
    const float* r0 = W0 + (size_t)wrow * 514;
    const float* r1 = W1 + (size_t)wrow * 514;
#pragma unroll
    for (int kk = 0; kk < 8; ++kk) {
      const int k0 = kk * 32 + kq * 8;
      f16x8 a, bx, a1, bx1;
#pragma unroll
      for (int j = 0; j < 8; ++j) {
        a[j]   = (_Float16)r0[k0 + j];
        bx[j]  = (_Float16)r0[256 + k0 + j];
        a1[j]  = (_Float16)r1[k0 + j];
        bx1[j] = (_Float16)r1[256 + k0 + j];
      }
      w0s[kk] = a; w0x[kk] = bx; w1s[kk] = a1; w1x[kk] = bx1;
    }
    w0pa = r0[512]; w0pb = r0[513];
    w1pa = r1[512]; w1pb = r1[513];
  }

  // ---- raw recurrence state (fp32, register-resident) ----
  float raw0[4], raw1[4];
#pragma unroll
  for (int r = 0; r < 4; ++r) { raw0[r] = hs[ocg]; raw1[r] = hs[256 + ocg]; }

  int alive = 1;

  // ---- init: fill h0 LDS (all 256 cols, broadcast rows) ----
#pragma unroll
  for (int i = 0; i < 4; ++i) {
    const int rc = tid + 512 * i;           // 0..2047 = 16 rows x 128 pairs
    const int r_ = rc >> 7, cp_ = rc & 127;
    union { _Float16 h; unsigned short u; } e0, e1;
    e0.h = (_Float16)hs[2 * cp_]; e1.h = (_Float16)hs[2 * cp_ + 1];
    h0u[r_][cp_] = (unsigned)e0.u | ((unsigned)e1.u << 16);
  }

  // ---- init publish: own-quarter tagged h0 cells + partials, tag 1 ----
  {
    const int r_ = tid >> 5, p_ = tid & 31;
    const int col = 64 * q + 2 * p_;
    union { _Float16 h; unsigned short u; } e0, e1;
    e0.h = (_Float16)hs[col]; e1.h = (_Float16)hs[col + 1];
    const unsigned dw = (unsigned)e0.u | ((unsigned)e1.u << 16);
    AS(g_st0 + (size_t)(b * 4 + q) * 512 + r_ * 32 + p_,
       (1ull << 32) | (unsigned long long)dw);
    if (tid < 64) {
      const int c_ = 64 * q + tid;
      AS(g_pa0 + (size_t)c_ * 4 + b,
         (1ull << 32) | (unsigned long long)__float_as_uint(16.f * hs[c_]));
    }
  }
  __syncthreads();

  // ---- x prefetch for t=0 ----
  f32x4 xf[16];
  const int arow = 16 * b + n;
  {
    const float* xp = xg + (size_t)arow * S_SEQ * 256 + kq * 8;
#pragma unroll
    for (int kk = 0; kk < 8; ++kk) {
      xf[2 * kk]     = *(const f32x4*)(xp + kk * 32);
      xf[2 * kk + 1] = *(const f32x4*)(xp + kk * 32 + 4);
    }
  }

  for (int t = 0; t < T_TOT; ++t) {
    const float pe0 = (float)(t + 1);
    const float pe1 = (pe0 - 1028.5f) * (1.0f / 1028.5f);
    const int have_x = (t < S_SEQ);

    // ---------------- phase A: o1 = (h1 + calc(h0c, s, W0)) * 0.5 ----------
    {
      f32x4 acc0, acc1;
      const float pt = pe0 * w0pa + pe1 * w0pb;
      acc0[0] = pt; acc0[1] = pt; acc0[2] = pt; acc0[3] = pt;
      acc1[0] = 0.f; acc1[1] = 0.f; acc1[2] = 0.f; acc1[3] = 0.f;
      // x part BEFORE the poll: overlaps the spin / off the critical path.
      if (have_x) {
#pragma unroll
        for (int kk = 0; kk < 8; ++kk) {
          f16x8 af;
#pragma unroll
          for (int j = 0; j < 4; ++j) {
            af[j]     = (_Float16)xf[2 * kk][j];
            af[4 + j] = (_Float16)xf[2 * kk + 1][j];
          }
          if (kk & 1)
            acc1 = __builtin_amdgcn_mfma_f32_16x16x32_f16(af, w0x[kk], acc1,
                                                          0, 0, 0);
          else
            acc0 = __builtin_amdgcn_mfma_f32_16x16x32_f16(af, w0x[kk], acc0,
                                                          0, 0, 0);
        }
      }
      PHASE(w0s, h0u, h1u, g_st0, g_pa0, 2 * t + 1, g_st1, g_pa1, 2 * t + 2,
            raw1);
    }

    // ---------------- phase B: o0 = (h0 + calc(o1c, s, W1)) * 0.5 ----------
    {
      f32x4 acc0, acc1;
      const float pt = pe0 * w1pa + pe1 * w1pb;
      acc0[0] = pt; acc0[1] = pt; acc0[2] = pt; acc0[3] = pt;
      acc1[0] = 0.f; acc1[1] = 0.f; acc1[2] = 0.f; acc1[3] = 0.f;
      if (have_x) {
#pragma unroll
        for (int kk = 0; kk < 8; ++kk) {  // re-convert xf (keeps VGPRs low)
          f16x8 af;
#pragma unroll
          for (int j = 0; j < 4; ++j) {
            af[j]     = (_Float16)xf[2 * kk][j];
            af[4 + j] = (_Float16)xf[2 * kk + 1][j];
          }
          if (kk & 1)
            acc1 = __builtin_amdgcn_mfma_f32_16x16x32_f16(af, w1x[kk], acc1,
                                                          0, 0, 0);
          else
            acc0 = __builtin_amdgcn_mfma_f32_16x16x32_f16(af, w1x[kk], acc0,
                                                          0, 0, 0);
        }
      }
      // prefetch x(t+1): in flight across poll B + phase-A conversion.
      if (t + 1 < S_SEQ) {
        const float* xp = xg + ((size_t)arow * S_SEQ + (t + 1)) * 256 + kq * 8;
#pragma unroll
        for (int kk = 0; kk < 8; ++kk) {
          xf[2 * kk]     = *(const f32x4*)(xp + kk * 32);
          xf[2 * kk + 1] = *(const f32x4*)(xp + kk * 32 + 4);
        }
      }
      PHASE(w1s, h1u, h0u, g_st1, g_pa1, 2 * t + 2, g_st0, g_pa0, 2 * t + 3,
            raw0);
    }
  }

  // ---- final h = [o0 | o1] fp32 ----
  if (n < 8) {
#pragma unroll
    for (int r = 0; r < 4; ++r) {
      const int row = 16 * b + kq * 4 + r;
      out[(size_t)row * 512 + ocg] = raw0[r];
      out[(size_t)row * 512 + 256 + ocg] = raw1[r];
    }
  }
}

#undef PHASE
#undef TOK
#undef AS
#undef AL

extern "C" void kernel_launch(void* const* d_in, const int* in_sizes, int n_in,
                              void* d_out, int out_size, void* d_ws, size_t ws_size,
                              hipStream_t stream) {
  (void)in_sizes; (void)n_in; (void)out_size; (void)d_ws; (void)ws_size;
  const float* x  = (const float*)d_in[0];
  const float* hs = (const float*)d_in[1];
  const float* W0 = (const float*)d_in[2];
  const float* W1 = (const float*)d_in[3];
  float* out = (float*)d_out;

  // prologue kernel zeroes the tagged exchange globals (stream-ordered;
  // replayed per graph iteration -> tags reset each run). No workspace use.
  init_ws<<<dim3(32), dim3(256), 0, stream>>>();
  rnn_kernel<<<dim3(16), dim3(512), 0, stream>>>(x, hs, W0, W1, out);
}